// Round 12
// baseline (168.006 us; speedup 1.0000x reference)
//
#include <hip/hip_runtime.h>
#include <hip/hip_bf16.h>
#include <cstdint>
#include <cstddef>

// CRF NLL forward. B=256, T=512, L=64.
// R12: T-split x2 -> 16 chunks x 32 steps (templated CH). R10/R11 showed the
// pass1 wall (~100us) >> per-SIMD pipe work (~17us VALU + 8us MFMA): the
// kernel is residency/latency-bound (4 blocks/CU dispatched, 31% occupancy,
// 64-step serial chain). CH=16 doubles dispatch to 8/CU (6 resident on LDS)
// and halves the per-wave chain. Falls back to CH=8 (== R11 exactly) if
// ws_size < 33MB+.
// Core (verified R6..R11): MFMA 16x16x32 bf16, sigma-mapped stationary A in
// regs, J-split 2 waves x 32 cols, kappa-only renorm, G stored in pass2
// A-frag order; pass2 chains alpha0 through the CH chunk matrices.

constexpr int Bc = 256, Tc = 512, Lc = 64;
#define LOG64F 4.1588830833596715f

typedef __attribute__((ext_vector_type(8))) short v8s;   // 8 bf16
typedef __attribute__((ext_vector_type(4))) float v4f;
typedef __attribute__((ext_vector_type(4))) unsigned int v4u;

__device__ __forceinline__ float lane_bcast(float v, int lane) {
    return __uint_as_float(__builtin_amdgcn_readlane(__float_as_uint(v), lane));
}
__device__ __forceinline__ int lane_bcast_i(int v, int lane) {
    return __builtin_amdgcn_readlane(v, lane);
}
__device__ __forceinline__ unsigned pk2(float x, float y) {
    __hip_bfloat162 h = __float22bfloat162_rn(make_float2(x, y));
    unsigned r; __builtin_memcpy(&r, &h, 4); return r;
}
__device__ __forceinline__ v8s as_v8s(v4u u) {
    v8s r; __builtin_memcpy(&r, &u, 16); return r;
}
__device__ __forceinline__ unsigned short bf16b(float x) {
    __hip_bfloat16 h = __float2bfloat16(x);
    unsigned short r; __builtin_memcpy(&r, &h, 2); return r;
}

// ---------------- Pass 1 ----------------
template<int CH>
__global__ __launch_bounds__(256, 4) void crf_pass1(
    const float* __restrict__ y_true,
    const float* __restrict__ y_pred,
    const float* __restrict__ trans,
    unsigned short* __restrict__ wsm,
    float* __restrict__ wss)
{
    constexpr int S = Tc / CH;            // steps per chunk
    const int tid = threadIdx.x, lane = tid & 63, wv = tid >> 6;
    const int w = blockIdx.x * 4 + wv;
    const int batch = w / (2 * CH);
    const int chunk = (w >> 1) % CH;
    const int h = w & 1;
    const int q = lane >> 4, m16 = lane & 15;
    const int rsub = q, csub = m16;

    __shared__ alignas(16) unsigned char smem_raw[16384];  // strans, then G scatter
    float* strans = (float*)smem_raw;
    __shared__ alignas(16) float fbuf[4][2][4][Lc];        // 8 KB

    {   // stage trans with all 256 threads
        const v4f* t4 = (const v4f*)trans;
        #pragma unroll
        for (int k = 0; k < 4; ++k) {
            v4f v = t4[k * 256 + tid];
            *(v4f*)&strans[(k * 256 + tid) * 4] = v;
        }
    }
    __syncthreads();

    // Stationary A operands: Areg[I][K] elem jj = exp(trans[sig][16I+m16]),
    // sig=(jj&3)+4q+16(jj>>2)+32K (verified mapping).
    v8s Areg[4][2];
    #pragma unroll
    for (int I = 0; I < 4; ++I) {
        #pragma unroll
        for (int K = 0; K < 2; ++K) {
            float e[8];
            #pragma unroll
            for (int jj = 0; jj < 8; ++jj) {
                const int sig = (jj & 3) + 4 * q + 16 * (jj >> 2) + 32 * K;
                e[jj] = __expf(strans[sig * Lc + 16 * I + m16]);
            }
            v4u u;
            u.x = pk2(e[0], e[1]); u.y = pk2(e[2], e[3]);
            u.z = pk2(e[4], e[5]); u.w = pk2(e[6], e[7]);
            Areg[I][K] = as_v8s(u);
        }
    }

    const float* yp = y_pred + (size_t)batch * Tc * Lc;
    const float* yt = y_true + (size_t)batch * Tc * Lc;
    const v4f* yp4 = (const v4f*)yp;
    const v4f* yt4 = (const v4f*)yt;

    const int base = chunk * S;           // boundary row
    const int r0 = base + 1;
    float psum = 0.0f, tsum = 0.0f, c = 0.0f;
    int lbl_carry = 0;
    if (h == 0) {
        const float bt = yt[base * Lc + lane];
        lbl_carry = (int)__builtin_ctzll(__ballot(bt > 0.5f));
    }

    auto ld4 = [&](const v4f* p, int baseRow) -> v4f {
        int r = baseRow + rsub; r = (r < Tc - 1) ? r : (Tc - 1);
        return p[r * 16 + csub];
    };

    const v4f z4 = {0.f, 0.f, 0.f, 0.f};
    v4f cyp = ld4(yp4, r0), nyp = ld4(yp4, r0 + 4);
    v4f cyt = z4, nyt = z4;
    if (h == 0) { cyt = ld4(yt4, r0); nyt = ld4(yt4, r0 + 4); }

    {   // prologue F rows r0..r0+3 (kappa-only; all real rows for every chunk)
        const float k0 = lane_bcast(cyp.x, 0)  + LOG64F;
        const float k1 = lane_bcast(cyp.x, 16) + LOG64F;
        const float k2 = lane_bcast(cyp.x, 32) + LOG64F;
        const float k3 = lane_bcast(cyp.x, 48) + LOG64F;
        c += ((k0 + k1) + (k2 + k3));
        const float kk = (rsub & 1) ? ((rsub & 2) ? k3 : k1)
                                    : ((rsub & 2) ? k2 : k0);
        v4f f;
        f.x = __expf(cyp.x - kk); f.y = __expf(cyp.y - kk);
        f.z = __expf(cyp.z - kk); f.w = __expf(cyp.w - kk);
        *(v4f*)&fbuf[wv][0][rsub][4 * csub] = f;
    }

    // B = identity columns Jg = 2h + Jl
    v8s Bfr[2][2];
    #pragma unroll
    for (int Kc = 0; Kc < 2; ++Kc) {
        #pragma unroll
        for (int Jl = 0; Jl < 2; ++Jl) {
            v8s bb;
            #pragma unroll
            for (int jj = 0; jj < 8; ++jj) {
                const bool one = (m16 == 4 * q + (jj & 3)) &&
                                 (2 * h + Jl == (jj >> 2) + 2 * Kc);
                bb[jj] = one ? (short)0x3F80 : (short)0;
            }
            Bfr[Kc][Jl] = bb;
        }
    }

    v4f P[4][2];
    #pragma unroll
    for (int I = 0; I < 4; ++I) { P[I][0] = z4; P[I][1] = z4; }
    int par = 0;

    auto mstep = [&](int s) {
        #pragma unroll
        for (int I = 0; I < 4; ++I) {
            const v4f F = *(const v4f*)&fbuf[wv][par][s][16 * I + 4 * q];
            #pragma unroll
            for (int Jl = 0; Jl < 2; ++Jl) {
                v4f a = __builtin_amdgcn_mfma_f32_16x16x32_bf16(Areg[I][0], Bfr[0][Jl], z4, 0, 0, 0);
                a = __builtin_amdgcn_mfma_f32_16x16x32_bf16(Areg[I][1], Bfr[1][Jl], a, 0, 0, 0);
                P[I][Jl] = a * F;
            }
        }
        #pragma unroll
        for (int Kc = 0; Kc < 2; ++Kc) {
            #pragma unroll
            for (int Jl = 0; Jl < 2; ++Jl) {
                v4u u;
                u.x = pk2(P[2 * Kc][Jl].x,     P[2 * Kc][Jl].y);
                u.y = pk2(P[2 * Kc][Jl].z,     P[2 * Kc][Jl].w);
                u.z = pk2(P[2 * Kc + 1][Jl].x, P[2 * Kc + 1][Jl].y);
                u.w = pk2(P[2 * Kc + 1][Jl].z, P[2 * Kc + 1][Jl].w);
                Bfr[Kc][Jl] = as_v8s(u);
            }
        }
    };

    auto scores4 = [&]() {
        psum = fmaf(cyp.x, cyt.x, psum); psum = fmaf(cyp.y, cyt.y, psum);
        psum = fmaf(cyp.z, cyt.z, psum); psum = fmaf(cyp.w, cyt.w, psum);
        const float has = fmaxf(fmaxf(cyt.x, cyt.y), fmaxf(cyt.z, cyt.w));
        int lidx = 0;
        lidx = (cyt.y > 0.5f) ? 1 : lidx;
        lidx = (cyt.z > 0.5f) ? 2 : lidx;
        lidx = (cyt.w > 0.5f) ? 3 : lidx;
        const unsigned long long m = __ballot(has > 0.5f);
        const int ln0 = (int)__builtin_ctz((unsigned)(m & 0xFFFFull));
        const int ln1 = (int)__builtin_ctz((unsigned)((m >> 16) & 0xFFFFull));
        const int ln2 = (int)__builtin_ctz((unsigned)((m >> 32) & 0xFFFFull));
        const int ln3 = (int)__builtin_ctz((unsigned)(m >> 48));
        const int lbl0 = 4 * ln0 + lane_bcast_i(lidx, ln0);
        const int lbl1 = 4 * ln1 + lane_bcast_i(lidx, 16 + ln1);
        const int lbl2 = 4 * ln2 + lane_bcast_i(lidx, 32 + ln2);
        const int lbl3 = 4 * ln3 + lane_bcast_i(lidx, 48 + ln3);
        const int lpA = (rsub & 2) ? lbl1 : lbl_carry;
        const int lpB = (rsub & 2) ? lbl2 : lbl0;
        const int lp  = (rsub & 1) ? lpB : lpA;
        lbl_carry = lbl3;
        const v4f tr = *(const v4f*)&strans[lp * Lc + 4 * csub];
        tsum = fmaf(cyt.x, tr.x, tsum); tsum = fmaf(cyt.y, tr.y, tsum);
        tsum = fmaf(cyt.z, tr.z, tsum); tsum = fmaf(cyt.w, tr.w, tsum);
    };

    #pragma unroll 1
    for (int bi = 0; bi < S / 4 - 1; ++bi) {
        const int rb = r0 + 4 * bi;
        const v4f lyp = ld4(yp4, rb + 8);
        v4f lyt = z4;
        if (h == 0) lyt = ld4(yt4, rb + 8);

        if (h == 0) scores4();
        mstep(0); mstep(1); mstep(2); mstep(3);

        {   // postamble: kappa-only F build for rows rb+4..rb+7
            const float k0 = lane_bcast(nyp.x, 0)  + LOG64F;
            const float k1 = lane_bcast(nyp.x, 16) + LOG64F;
            const float k2 = lane_bcast(nyp.x, 32) + LOG64F;
            const float k3 = lane_bcast(nyp.x, 48) + LOG64F;
            c += ((k0 + k1) + k2);
            if (rb + 7 <= Tc - 1) c += k3;          // phantom row-512 guard
            const float kk = (rsub & 1) ? ((rsub & 2) ? k3 : k1)
                                        : ((rsub & 2) ? k2 : k0);
            v4f f;
            f.x = __expf(nyp.x - kk); f.y = __expf(nyp.y - kk);
            f.z = __expf(nyp.z - kk); f.w = __expf(nyp.w - kk);
            *(v4f*)&fbuf[wv][par ^ 1][rsub][4 * csub] = f;
        }
        par ^= 1;
        cyp = nyp; nyp = lyp;
        if (h == 0) { cyt = nyt; nyt = lyt; }
    }

    if (chunk < CH - 1) {
        if (h == 0) scores4();
        mstep(0); mstep(1); mstep(2); mstep(3);
    } else {
        if (h == 0) {   // 3 real tail rows (509..511), rsub3 phantom
            float pd = cyp.x * cyt.x;
            pd = fmaf(cyp.y, cyt.y, pd); pd = fmaf(cyp.z, cyt.z, pd); pd = fmaf(cyp.w, cyt.w, pd);
            const float has = fmaxf(fmaxf(cyt.x, cyt.y), fmaxf(cyt.z, cyt.w));
            int lidx = 0;
            lidx = (cyt.y > 0.5f) ? 1 : lidx;
            lidx = (cyt.z > 0.5f) ? 2 : lidx;
            lidx = (cyt.w > 0.5f) ? 3 : lidx;
            const unsigned long long m = __ballot(has > 0.5f);
            const int ln0 = (int)__builtin_ctz((unsigned)(m & 0xFFFFull));
            const int ln1 = (int)__builtin_ctz((unsigned)((m >> 16) & 0xFFFFull));
            const int lbl0 = 4 * ln0 + lane_bcast_i(lidx, ln0);
            const int lbl1 = 4 * ln1 + lane_bcast_i(lidx, 16 + ln1);
            const int lpA = (rsub & 2) ? lbl1 : lbl_carry;
            const int lp  = (rsub & 1) ? lbl0 : lpA;
            const v4f tr = *(const v4f*)&strans[lp * Lc + 4 * csub];
            float td = cyt.x * tr.x;
            td = fmaf(cyt.y, tr.y, td); td = fmaf(cyt.z, tr.z, td); td = fmaf(cyt.w, tr.w, td);
            if (rsub < 3) { psum += pd; tsum += td; }
        }
        mstep(0); mstep(1); mstep(2);
    }

    // ---- G store in pass2 A-frag order, via LDS scatter (strans now dead) ----
    __syncthreads();   // all waves done reading strans
    unsigned short* myblob = ((unsigned short*)smem_raw) + wv * 2048;
    #pragma unroll
    for (int I = 0; I < 4; ++I) {
        #pragma unroll
        for (int Jl = 0; Jl < 2; ++Jl) {
            float v[4] = {P[I][Jl].x, P[I][Jl].y, P[I][Jl].z, P[I][Jl].w};
            #pragma unroll
            for (int r = 0; r < 4; ++r) {
                const int li = I * 512 + (16 * (m16 >> 2) + 4 * q + r) * 8
                             + 4 * Jl + (m16 & 3);
                myblob[li] = bf16b(v[r]);
            }
        }
    }
    {   // coalesced copy-out: this wave's 4 KB
        const int I = lane >> 4;
        const unsigned short* src = myblob + lane * 32;
        unsigned short* dst = wsm + (size_t)(batch * CH + chunk) * 4096
                            + I * 1024 + h * 512 + (lane & 15) * 32;
        #pragma unroll
        for (int t = 0; t < 4; ++t)
            *(v4u*)(dst + t * 8) = *(const v4u*)(src + t * 8);
    }

    if (h == 0) {
        #pragma unroll
        for (int k = 1; k < 64; k <<= 1) psum += __shfl_xor(psum, k);
        #pragma unroll
        for (int k = 1; k < 64; k <<= 1) tsum += __shfl_xor(tsum, k);
        if (lane == 0) {
            float* s = wss + (batch * CH + chunk) * 4;
            s[0] = c; s[1] = psum; s[2] = tsum;
        }
    }
}

// ---------------- Pass 2 ----------------
template<int CH>
__global__ __launch_bounds__(64, 1) void crf_pass2(
    const float* __restrict__ y_true,
    const float* __restrict__ y_pred,
    const unsigned short* __restrict__ wsm,
    const float* __restrict__ wss,
    float* __restrict__ out)
{
    const int lane = threadIdx.x;
    const int b = blockIdx.x;
    const int q = lane >> 4;

    __shared__ float arow[Lc];

    const float* yp = y_pred + (size_t)b * Tc * Lc;
    const float yp0 = yp[lane];
    float psum = yp0 * (((const float*)(y_true + (size_t)b * Tc * Lc))[lane]);
    float tsum = 0.0f;
    float c = lane_bcast(yp0, 0);
    arow[lane] = __expf(yp0 - c);

    v8s Bfr[2];
    #pragma unroll
    for (int cc = 0; cc < 2; ++cc) {
        const v4f lo = *(const v4f*)&arow[32 * cc + 4 * q];
        const v4f hi = *(const v4f*)&arow[32 * cc + 16 + 4 * q];
        v4u u;
        u.x = pk2(lo.x, lo.y); u.y = pk2(lo.z, lo.w);
        u.z = pk2(hi.x, hi.y); u.w = pk2(hi.z, hi.w);
        Bfr[cc] = as_v8s(u);
    }

    const v4f z4 = {0.f, 0.f, 0.f, 0.f};
    v4f P0 = z4, P1 = z4, P2 = z4, P3 = z4;

    v4u Abuf[2][8];
    {
        const v4u* g0 = (const v4u*)(wsm + (size_t)(b * CH) * 4096);
        #pragma unroll
        for (int s = 0; s < 8; ++s) Abuf[0][s] = g0[s * 64 + lane];
    }

    #pragma unroll
    for (int kk = 0; kk < CH; ++kk) {
        const int cur = kk & 1, nxt = cur ^ 1;
        if (kk < CH - 1) {
            const v4u* g1 = (const v4u*)(wsm + (size_t)(b * CH + kk + 1) * 4096);
            #pragma unroll
            for (int s = 0; s < 8; ++s) Abuf[nxt][s] = g1[s * 64 + lane];
        }
        v4f a0 = __builtin_amdgcn_mfma_f32_16x16x32_bf16(as_v8s(Abuf[cur][0]), Bfr[0], z4, 0, 0, 0);
        v4f a1 = __builtin_amdgcn_mfma_f32_16x16x32_bf16(as_v8s(Abuf[cur][2]), Bfr[0], z4, 0, 0, 0);
        v4f a2 = __builtin_amdgcn_mfma_f32_16x16x32_bf16(as_v8s(Abuf[cur][4]), Bfr[0], z4, 0, 0, 0);
        v4f a3 = __builtin_amdgcn_mfma_f32_16x16x32_bf16(as_v8s(Abuf[cur][6]), Bfr[0], z4, 0, 0, 0);
        a0 = __builtin_amdgcn_mfma_f32_16x16x32_bf16(as_v8s(Abuf[cur][1]), Bfr[1], a0, 0, 0, 0);
        a1 = __builtin_amdgcn_mfma_f32_16x16x32_bf16(as_v8s(Abuf[cur][3]), Bfr[1], a1, 0, 0, 0);
        a2 = __builtin_amdgcn_mfma_f32_16x16x32_bf16(as_v8s(Abuf[cur][5]), Bfr[1], a2, 0, 0, 0);
        a3 = __builtin_amdgcn_mfma_f32_16x16x32_bf16(as_v8s(Abuf[cur][7]), Bfr[1], a3, 0, 0, 0);

        const float sc = lane_bcast(a0.x, 0);
        const float inv = 1.0f / sc;
        c += __logf(sc);
        P0 = a0 * inv; P1 = a1 * inv; P2 = a2 * inv; P3 = a3 * inv;
        {
            v4u u;
            u.x = pk2(P0.x, P0.y); u.y = pk2(P0.z, P0.w);
            u.z = pk2(P1.x, P1.y); u.w = pk2(P1.z, P1.w);
            Bfr[0] = as_v8s(u);
        }
        {
            v4u u;
            u.x = pk2(P2.x, P2.y); u.y = pk2(P2.z, P2.w);
            u.z = pk2(P3.x, P3.y); u.w = pk2(P3.z, P3.w);
            Bfr[1] = as_v8s(u);
        }
    }

    float ftot = (((P0.x + P0.y) + (P0.z + P0.w)) + ((P1.x + P1.y) + (P1.z + P1.w)))
               + (((P2.x + P2.y) + (P2.z + P2.w)) + ((P3.x + P3.y) + (P3.z + P3.w)));
    ftot += __shfl_xor(ftot, 16);
    ftot += __shfl_xor(ftot, 32);

    #pragma unroll
    for (int k = 1; k < 64; k <<= 1) psum += __shfl_xor(psum, k);

    if (lane == 0) {
        float cs = c, ps = psum, ts = tsum;
        #pragma unroll
        for (int kk = 0; kk < CH; ++kk) {
            const float* s = wss + (b * CH + kk) * 4;
            cs += s[0]; ps += s[1]; ts += s[2];
        }
        out[b] = -(ps + ts - (cs + __logf(ftot)));
    }
}

extern "C" void kernel_launch(void* const* d_in, const int* in_sizes, int n_in,
                              void* d_out, int out_size, void* d_ws, size_t ws_size,
                              hipStream_t stream) {
    const float* y_true = (const float*)d_in[0];
    const float* y_pred = (const float*)d_in[1];
    const float* trans  = (const float*)d_in[2];
    float* outp = (float*)d_out;
    unsigned short* wsm = (unsigned short*)d_ws;

    // CH=16 needs 256*16*8KB = 32MB for G + 256KB scalars.
    if (ws_size >= (34ull << 20)) {
        float* wss = (float*)((char*)d_ws + (32ull << 20));
        crf_pass1<16><<<dim3(2048), dim3(256), 0, stream>>>(y_true, y_pred, trans, wsm, wss);
        crf_pass2<16><<<dim3(256),  dim3(64),  0, stream>>>(y_true, y_pred, wsm, wss, outp);
    } else {
        float* wss = (float*)((char*)d_ws + (16ull << 20));
        crf_pass1<8><<<dim3(1024), dim3(256), 0, stream>>>(y_true, y_pred, trans, wsm, wss);
        crf_pass2<8><<<dim3(256),  dim3(64),  0, stream>>>(y_true, y_pred, wsm, wss, outp);
    }
}

// Round 13
// 159.502 us; speedup vs baseline: 1.0533x; 1.0533x over previous
//
#include <hip/hip_runtime.h>
#include <hip/hip_bf16.h>
#include <cstdint>
#include <cstddef>

// CRF NLL forward. B=256, T=512, L=64.
// R13 = R12 (CH=16 T-split, J-split, kappa-only renorm) with the bf16 pack
// replaced by a 3-inst HW path: u+0x8000 round + v_perm_b32 splice.
// Theory: HIP's __float2bfloat16 lowers to ~6-13 VALU insts (software RNE +
// NaN handling); 32 packed values/step ~= 200 phantom VALU insts/step ==
// the observed 267/step vs ~50 useful (VALUBusy 60%, MfmaUtil 30%, wall
// pinned at 95us across R10/R11/R12). Inputs are positive finite exp-domain
// values: no NaN path needed; round-half-up vs RNE differs only at exact
// ties (negligible vs existing bf16 noise).

constexpr int Bc = 256, Tc = 512, Lc = 64;
#define LOG64F 4.1588830833596715f

typedef __attribute__((ext_vector_type(8))) short v8s;   // 8 bf16
typedef __attribute__((ext_vector_type(4))) float v4f;
typedef __attribute__((ext_vector_type(4))) unsigned int v4u;

__device__ __forceinline__ float lane_bcast(float v, int lane) {
    return __uint_as_float(__builtin_amdgcn_readlane(__float_as_uint(v), lane));
}
__device__ __forceinline__ int lane_bcast_i(int v, int lane) {
    return __builtin_amdgcn_readlane(v, lane);
}
// fast bf16x2 pack: low16 = bf16(x), high16 = bf16(y). 3 VALU insts.
__device__ __forceinline__ unsigned pk2(float x, float y) {
    const unsigned ux = __float_as_uint(x) + 0x8000u;
    const unsigned uy = __float_as_uint(y) + 0x8000u;
    return __builtin_amdgcn_perm(uy, ux, 0x07060302u);
}
__device__ __forceinline__ v8s as_v8s(v4u u) {
    v8s r; __builtin_memcpy(&r, &u, 16); return r;
}
__device__ __forceinline__ unsigned short bf16b(float x) {
    return (unsigned short)((__float_as_uint(x) + 0x8000u) >> 16);
}

// ---------------- Pass 1 ----------------
template<int CH>
__global__ __launch_bounds__(256, 4) void crf_pass1(
    const float* __restrict__ y_true,
    const float* __restrict__ y_pred,
    const float* __restrict__ trans,
    unsigned short* __restrict__ wsm,
    float* __restrict__ wss)
{
    constexpr int S = Tc / CH;            // steps per chunk
    const int tid = threadIdx.x, lane = tid & 63, wv = tid >> 6;
    const int w = blockIdx.x * 4 + wv;
    const int batch = w / (2 * CH);
    const int chunk = (w >> 1) % CH;
    const int h = w & 1;
    const int q = lane >> 4, m16 = lane & 15;
    const int rsub = q, csub = m16;

    __shared__ alignas(16) unsigned char smem_raw[16384];  // strans, then G scatter
    float* strans = (float*)smem_raw;
    __shared__ alignas(16) float fbuf[4][2][4][Lc];        // 8 KB

    {   // stage trans with all 256 threads
        const v4f* t4 = (const v4f*)trans;
        #pragma unroll
        for (int k = 0; k < 4; ++k) {
            v4f v = t4[k * 256 + tid];
            *(v4f*)&strans[(k * 256 + tid) * 4] = v;
        }
    }
    __syncthreads();

    // Stationary A operands: Areg[I][K] elem jj = exp(trans[sig][16I+m16]),
    // sig=(jj&3)+4q+16(jj>>2)+32K (verified mapping).
    v8s Areg[4][2];
    #pragma unroll
    for (int I = 0; I < 4; ++I) {
        #pragma unroll
        for (int K = 0; K < 2; ++K) {
            float e[8];
            #pragma unroll
            for (int jj = 0; jj < 8; ++jj) {
                const int sig = (jj & 3) + 4 * q + 16 * (jj >> 2) + 32 * K;
                e[jj] = __expf(strans[sig * Lc + 16 * I + m16]);
            }
            v4u u;
            u.x = pk2(e[0], e[1]); u.y = pk2(e[2], e[3]);
            u.z = pk2(e[4], e[5]); u.w = pk2(e[6], e[7]);
            Areg[I][K] = as_v8s(u);
        }
    }

    const float* yp = y_pred + (size_t)batch * Tc * Lc;
    const float* yt = y_true + (size_t)batch * Tc * Lc;
    const v4f* yp4 = (const v4f*)yp;
    const v4f* yt4 = (const v4f*)yt;

    const int base = chunk * S;           // boundary row
    const int r0 = base + 1;
    float psum = 0.0f, tsum = 0.0f, c = 0.0f;
    int lbl_carry = 0;
    if (h == 0) {
        const float bt = yt[base * Lc + lane];
        lbl_carry = (int)__builtin_ctzll(__ballot(bt > 0.5f));
    }

    auto ld4 = [&](const v4f* p, int baseRow) -> v4f {
        int r = baseRow + rsub; r = (r < Tc - 1) ? r : (Tc - 1);
        return p[r * 16 + csub];
    };

    const v4f z4 = {0.f, 0.f, 0.f, 0.f};
    v4f cyp = ld4(yp4, r0), nyp = ld4(yp4, r0 + 4);
    v4f cyt = z4, nyt = z4;
    if (h == 0) { cyt = ld4(yt4, r0); nyt = ld4(yt4, r0 + 4); }

    {   // prologue F rows r0..r0+3 (kappa-only; all real rows for every chunk)
        const float k0 = lane_bcast(cyp.x, 0)  + LOG64F;
        const float k1 = lane_bcast(cyp.x, 16) + LOG64F;
        const float k2 = lane_bcast(cyp.x, 32) + LOG64F;
        const float k3 = lane_bcast(cyp.x, 48) + LOG64F;
        c += ((k0 + k1) + (k2 + k3));
        const float kk = (rsub & 1) ? ((rsub & 2) ? k3 : k1)
                                    : ((rsub & 2) ? k2 : k0);
        v4f f;
        f.x = __expf(cyp.x - kk); f.y = __expf(cyp.y - kk);
        f.z = __expf(cyp.z - kk); f.w = __expf(cyp.w - kk);
        *(v4f*)&fbuf[wv][0][rsub][4 * csub] = f;
    }

    // B = identity columns Jg = 2h + Jl
    v8s Bfr[2][2];
    #pragma unroll
    for (int Kc = 0; Kc < 2; ++Kc) {
        #pragma unroll
        for (int Jl = 0; Jl < 2; ++Jl) {
            v8s bb;
            #pragma unroll
            for (int jj = 0; jj < 8; ++jj) {
                const bool one = (m16 == 4 * q + (jj & 3)) &&
                                 (2 * h + Jl == (jj >> 2) + 2 * Kc);
                bb[jj] = one ? (short)0x3F80 : (short)0;
            }
            Bfr[Kc][Jl] = bb;
        }
    }

    v4f P[4][2];
    #pragma unroll
    for (int I = 0; I < 4; ++I) { P[I][0] = z4; P[I][1] = z4; }
    int par = 0;

    auto mstep = [&](int s) {
        #pragma unroll
        for (int I = 0; I < 4; ++I) {
            const v4f F = *(const v4f*)&fbuf[wv][par][s][16 * I + 4 * q];
            #pragma unroll
            for (int Jl = 0; Jl < 2; ++Jl) {
                v4f a = __builtin_amdgcn_mfma_f32_16x16x32_bf16(Areg[I][0], Bfr[0][Jl], z4, 0, 0, 0);
                a = __builtin_amdgcn_mfma_f32_16x16x32_bf16(Areg[I][1], Bfr[1][Jl], a, 0, 0, 0);
                P[I][Jl] = a * F;
            }
        }
        #pragma unroll
        for (int Kc = 0; Kc < 2; ++Kc) {
            #pragma unroll
            for (int Jl = 0; Jl < 2; ++Jl) {
                v4u u;
                u.x = pk2(P[2 * Kc][Jl].x,     P[2 * Kc][Jl].y);
                u.y = pk2(P[2 * Kc][Jl].z,     P[2 * Kc][Jl].w);
                u.z = pk2(P[2 * Kc + 1][Jl].x, P[2 * Kc + 1][Jl].y);
                u.w = pk2(P[2 * Kc + 1][Jl].z, P[2 * Kc + 1][Jl].w);
                Bfr[Kc][Jl] = as_v8s(u);
            }
        }
    };

    auto scores4 = [&]() {
        psum = fmaf(cyp.x, cyt.x, psum); psum = fmaf(cyp.y, cyt.y, psum);
        psum = fmaf(cyp.z, cyt.z, psum); psum = fmaf(cyp.w, cyt.w, psum);
        const float has = fmaxf(fmaxf(cyt.x, cyt.y), fmaxf(cyt.z, cyt.w));
        int lidx = 0;
        lidx = (cyt.y > 0.5f) ? 1 : lidx;
        lidx = (cyt.z > 0.5f) ? 2 : lidx;
        lidx = (cyt.w > 0.5f) ? 3 : lidx;
        const unsigned long long m = __ballot(has > 0.5f);
        const int ln0 = (int)__builtin_ctz((unsigned)(m & 0xFFFFull));
        const int ln1 = (int)__builtin_ctz((unsigned)((m >> 16) & 0xFFFFull));
        const int ln2 = (int)__builtin_ctz((unsigned)((m >> 32) & 0xFFFFull));
        const int ln3 = (int)__builtin_ctz((unsigned)(m >> 48));
        const int lbl0 = 4 * ln0 + lane_bcast_i(lidx, ln0);
        const int lbl1 = 4 * ln1 + lane_bcast_i(lidx, 16 + ln1);
        const int lbl2 = 4 * ln2 + lane_bcast_i(lidx, 32 + ln2);
        const int lbl3 = 4 * ln3 + lane_bcast_i(lidx, 48 + ln3);
        const int lpA = (rsub & 2) ? lbl1 : lbl_carry;
        const int lpB = (rsub & 2) ? lbl2 : lbl0;
        const int lp  = (rsub & 1) ? lpB : lpA;
        lbl_carry = lbl3;
        const v4f tr = *(const v4f*)&strans[lp * Lc + 4 * csub];
        tsum = fmaf(cyt.x, tr.x, tsum); tsum = fmaf(cyt.y, tr.y, tsum);
        tsum = fmaf(cyt.z, tr.z, tsum); tsum = fmaf(cyt.w, tr.w, tsum);
    };

    #pragma unroll 1
    for (int bi = 0; bi < S / 4 - 1; ++bi) {
        const int rb = r0 + 4 * bi;
        const v4f lyp = ld4(yp4, rb + 8);
        v4f lyt = z4;
        if (h == 0) lyt = ld4(yt4, rb + 8);

        if (h == 0) scores4();
        mstep(0); mstep(1); mstep(2); mstep(3);

        {   // postamble: kappa-only F build for rows rb+4..rb+7
            const float k0 = lane_bcast(nyp.x, 0)  + LOG64F;
            const float k1 = lane_bcast(nyp.x, 16) + LOG64F;
            const float k2 = lane_bcast(nyp.x, 32) + LOG64F;
            const float k3 = lane_bcast(nyp.x, 48) + LOG64F;
            c += ((k0 + k1) + k2);
            if (rb + 7 <= Tc - 1) c += k3;          // phantom row-512 guard
            const float kk = (rsub & 1) ? ((rsub & 2) ? k3 : k1)
                                        : ((rsub & 2) ? k2 : k0);
            v4f f;
            f.x = __expf(nyp.x - kk); f.y = __expf(nyp.y - kk);
            f.z = __expf(nyp.z - kk); f.w = __expf(nyp.w - kk);
            *(v4f*)&fbuf[wv][par ^ 1][rsub][4 * csub] = f;
        }
        par ^= 1;
        cyp = nyp; nyp = lyp;
        if (h == 0) { cyt = nyt; nyt = lyt; }
    }

    if (chunk < CH - 1) {
        if (h == 0) scores4();
        mstep(0); mstep(1); mstep(2); mstep(3);
    } else {
        if (h == 0) {   // 3 real tail rows (509..511), rsub3 phantom
            float pd = cyp.x * cyt.x;
            pd = fmaf(cyp.y, cyt.y, pd); pd = fmaf(cyp.z, cyt.z, pd); pd = fmaf(cyp.w, cyt.w, pd);
            const float has = fmaxf(fmaxf(cyt.x, cyt.y), fmaxf(cyt.z, cyt.w));
            int lidx = 0;
            lidx = (cyt.y > 0.5f) ? 1 : lidx;
            lidx = (cyt.z > 0.5f) ? 2 : lidx;
            lidx = (cyt.w > 0.5f) ? 3 : lidx;
            const unsigned long long m = __ballot(has > 0.5f);
            const int ln0 = (int)__builtin_ctz((unsigned)(m & 0xFFFFull));
            const int ln1 = (int)__builtin_ctz((unsigned)((m >> 16) & 0xFFFFull));
            const int lbl0 = 4 * ln0 + lane_bcast_i(lidx, ln0);
            const int lbl1 = 4 * ln1 + lane_bcast_i(lidx, 16 + ln1);
            const int lpA = (rsub & 2) ? lbl1 : lbl_carry;
            const int lp  = (rsub & 1) ? lbl0 : lpA;
            const v4f tr = *(const v4f*)&strans[lp * Lc + 4 * csub];
            float td = cyt.x * tr.x;
            td = fmaf(cyt.y, tr.y, td); td = fmaf(cyt.z, tr.z, td); td = fmaf(cyt.w, tr.w, td);
            if (rsub < 3) { psum += pd; tsum += td; }
        }
        mstep(0); mstep(1); mstep(2);
    }

    // ---- G store in pass2 A-frag order, via LDS scatter (strans now dead) ----
    __syncthreads();   // all waves done reading strans
    unsigned short* myblob = ((unsigned short*)smem_raw) + wv * 2048;
    #pragma unroll
    for (int I = 0; I < 4; ++I) {
        #pragma unroll
        for (int Jl = 0; Jl < 2; ++Jl) {
            float v[4] = {P[I][Jl].x, P[I][Jl].y, P[I][Jl].z, P[I][Jl].w};
            #pragma unroll
            for (int r = 0; r < 4; ++r) {
                const int li = I * 512 + (16 * (m16 >> 2) + 4 * q + r) * 8
                             + 4 * Jl + (m16 & 3);
                myblob[li] = bf16b(v[r]);
            }
        }
    }
    {   // coalesced copy-out: this wave's 4 KB
        const int I = lane >> 4;
        const unsigned short* src = myblob + lane * 32;
        unsigned short* dst = wsm + (size_t)(batch * CH + chunk) * 4096
                            + I * 1024 + h * 512 + (lane & 15) * 32;
        #pragma unroll
        for (int t = 0; t < 4; ++t)
            *(v4u*)(dst + t * 8) = *(const v4u*)(src + t * 8);
    }

    if (h == 0) {
        #pragma unroll
        for (int k = 1; k < 64; k <<= 1) psum += __shfl_xor(psum, k);
        #pragma unroll
        for (int k = 1; k < 64; k <<= 1) tsum += __shfl_xor(tsum, k);
        if (lane == 0) {
            float* s = wss + (batch * CH + chunk) * 4;
            s[0] = c; s[1] = psum; s[2] = tsum;
        }
    }
}

// ---------------- Pass 2 ----------------
template<int CH>
__global__ __launch_bounds__(64, 1) void crf_pass2(
    const float* __restrict__ y_true,
    const float* __restrict__ y_pred,
    const unsigned short* __restrict__ wsm,
    const float* __restrict__ wss,
    float* __restrict__ out)
{
    const int lane = threadIdx.x;
    const int b = blockIdx.x;
    const int q = lane >> 4;

    __shared__ float arow[Lc];

    const float* yp = y_pred + (size_t)b * Tc * Lc;
    const float yp0 = yp[lane];
    float psum = yp0 * (((const float*)(y_true + (size_t)b * Tc * Lc))[lane]);
    float tsum = 0.0f;
    float c = lane_bcast(yp0, 0);
    arow[lane] = __expf(yp0 - c);

    v8s Bfr[2];
    #pragma unroll
    for (int cc = 0; cc < 2; ++cc) {
        const v4f lo = *(const v4f*)&arow[32 * cc + 4 * q];
        const v4f hi = *(const v4f*)&arow[32 * cc + 16 + 4 * q];
        v4u u;
        u.x = pk2(lo.x, lo.y); u.y = pk2(lo.z, lo.w);
        u.z = pk2(hi.x, hi.y); u.w = pk2(hi.z, hi.w);
        Bfr[cc] = as_v8s(u);
    }

    const v4f z4 = {0.f, 0.f, 0.f, 0.f};
    v4f P0 = z4, P1 = z4, P2 = z4, P3 = z4;

    v4u Abuf[2][8];
    {
        const v4u* g0 = (const v4u*)(wsm + (size_t)(b * CH) * 4096);
        #pragma unroll
        for (int s = 0; s < 8; ++s) Abuf[0][s] = g0[s * 64 + lane];
    }

    #pragma unroll
    for (int kk = 0; kk < CH; ++kk) {
        const int cur = kk & 1, nxt = cur ^ 1;
        if (kk < CH - 1) {
            const v4u* g1 = (const v4u*)(wsm + (size_t)(b * CH + kk + 1) * 4096);
            #pragma unroll
            for (int s = 0; s < 8; ++s) Abuf[nxt][s] = g1[s * 64 + lane];
        }
        v4f a0 = __builtin_amdgcn_mfma_f32_16x16x32_bf16(as_v8s(Abuf[cur][0]), Bfr[0], z4, 0, 0, 0);
        v4f a1 = __builtin_amdgcn_mfma_f32_16x16x32_bf16(as_v8s(Abuf[cur][2]), Bfr[0], z4, 0, 0, 0);
        v4f a2 = __builtin_amdgcn_mfma_f32_16x16x32_bf16(as_v8s(Abuf[cur][4]), Bfr[0], z4, 0, 0, 0);
        v4f a3 = __builtin_amdgcn_mfma_f32_16x16x32_bf16(as_v8s(Abuf[cur][6]), Bfr[0], z4, 0, 0, 0);
        a0 = __builtin_amdgcn_mfma_f32_16x16x32_bf16(as_v8s(Abuf[cur][1]), Bfr[1], a0, 0, 0, 0);
        a1 = __builtin_amdgcn_mfma_f32_16x16x32_bf16(as_v8s(Abuf[cur][3]), Bfr[1], a1, 0, 0, 0);
        a2 = __builtin_amdgcn_mfma_f32_16x16x32_bf16(as_v8s(Abuf[cur][5]), Bfr[1], a2, 0, 0, 0);
        a3 = __builtin_amdgcn_mfma_f32_16x16x32_bf16(as_v8s(Abuf[cur][7]), Bfr[1], a3, 0, 0, 0);

        const float sc = lane_bcast(a0.x, 0);
        const float inv = 1.0f / sc;
        c += __logf(sc);
        P0 = a0 * inv; P1 = a1 * inv; P2 = a2 * inv; P3 = a3 * inv;
        {
            v4u u;
            u.x = pk2(P0.x, P0.y); u.y = pk2(P0.z, P0.w);
            u.z = pk2(P1.x, P1.y); u.w = pk2(P1.z, P1.w);
            Bfr[0] = as_v8s(u);
        }
        {
            v4u u;
            u.x = pk2(P2.x, P2.y); u.y = pk2(P2.z, P2.w);
            u.z = pk2(P3.x, P3.y); u.w = pk2(P3.z, P3.w);
            Bfr[1] = as_v8s(u);
        }
    }

    float ftot = (((P0.x + P0.y) + (P0.z + P0.w)) + ((P1.x + P1.y) + (P1.z + P1.w)))
               + (((P2.x + P2.y) + (P2.z + P2.w)) + ((P3.x + P3.y) + (P3.z + P3.w)));
    ftot += __shfl_xor(ftot, 16);
    ftot += __shfl_xor(ftot, 32);

    #pragma unroll
    for (int k = 1; k < 64; k <<= 1) psum += __shfl_xor(psum, k);

    if (lane == 0) {
        float cs = c, ps = psum, ts = tsum;
        #pragma unroll
        for (int kk = 0; kk < CH; ++kk) {
            const float* s = wss + (b * CH + kk) * 4;
            cs += s[0]; ps += s[1]; ts += s[2];
        }
        out[b] = -(ps + ts - (cs + __logf(ftot)));
    }
}

extern "C" void kernel_launch(void* const* d_in, const int* in_sizes, int n_in,
                              void* d_out, int out_size, void* d_ws, size_t ws_size,
                              hipStream_t stream) {
    const float* y_true = (const float*)d_in[0];
    const float* y_pred = (const float*)d_in[1];
    const float* trans  = (const float*)d_in[2];
    float* outp = (float*)d_out;
    unsigned short* wsm = (unsigned short*)d_ws;

    // CH=16 needs 256*16*8KB = 32MB for G + 256KB scalars.
    if (ws_size >= (34ull << 20)) {
        float* wss = (float*)((char*)d_ws + (32ull << 20));
        crf_pass1<16><<<dim3(2048), dim3(256), 0, stream>>>(y_true, y_pred, trans, wsm, wss);
        crf_pass2<16><<<dim3(256),  dim3(64),  0, stream>>>(y_true, y_pred, wsm, wss, outp);
    } else {
        float* wss = (float*)((char*)d_ws + (16ull << 20));
        crf_pass1<8><<<dim3(1024), dim3(256), 0, stream>>>(y_true, y_pred, trans, wsm, wss);
        crf_pass2<8><<<dim3(256),  dim3(64),  0, stream>>>(y_true, y_pred, wsm, wss, outp);
    }
}